// Round 1
// baseline (148.069 us; speedup 1.0000x reference)
//
#include <hip/hip_runtime.h>
#include <stdint.h>

#define BATCH 32
#define H 384
#define W 384
#define DIM 64
#define WPR (W / 32)        // 12 words per row
#define SEGS (W / 64)       // 6 64-pixel segments per row
#define NPAT 512
#define BPI 8               // blocks per image
#define ROWS_PB (H / BPI)   // 48 rows per block
#define NPIX (BATCH * H * W)

// K1: LSB extraction + wave-wide bit packing. Also zero-inits d_out.
__global__ __launch_bounds__(256) void pack_bits_kernel(
    const float* __restrict__ alpha, uint32_t* __restrict__ words,
    float* __restrict__ out)
{
    int t = blockIdx.x * 256 + threadIdx.x;   // grid exactly covers NPIX
    if (t < BATCH * (DIM + 1)) out[t] = 0.0f; // harness poisons d_out with 0xAA
    float a = alpha[t];
    int bit = ((int)(a * 255.0f)) & 1;        // same fp32 mul + trunc as reference
    unsigned long long mask = __ballot(bit);  // lane i -> bit i (64-bit on CDNA)
    if ((threadIdx.x & 63) == 0) {
        ((unsigned long long*)words)[t >> 6] = mask; // 8B aligned, coalesced-ish
    }
}

// K2: per-image 512-bin pattern histogram (LDS) + channel contraction.
__global__ __launch_bounds__(256) void hist_feat_kernel(
    const uint32_t* __restrict__ words,
    const float* __restrict__ conv_w, const float* __restrict__ conv_b,
    const float* __restrict__ bn_g, const float* __restrict__ bn_b,
    const float* __restrict__ bn_m, const float* __restrict__ bn_v,
    float* __restrict__ out)
{
    __shared__ uint32_t lh[NPAT];
    __shared__ float facc[4][DIM];
    const int tid  = threadIdx.x;
    const int wave = tid >> 6;
    const int lane = tid & 63;
    const int img  = blockIdx.x / BPI;
    const int blk  = blockIdx.x % BPI;

    for (int i = tid; i < NPAT; i += 256) lh[i] = 0;
    __syncthreads();

    const uint32_t* wb = words + img * (H * WPR);

    // Phase 1: histogram. 48 rows x 6 segments = 288 wave-tasks, 72 per wave.
    for (int task = wave; task < ROWS_PB * SEGS; task += 4) {
        int r   = blk * ROWS_PB + task / SEGS;
        int seg = task - (task / SEGS) * SEGS;
        int w0  = seg * 2;                    // first word of this 64-px segment
        uint32_t pat = 0;
        #pragma unroll
        for (int dy = 0; dy < 3; ++dy) {
            int y = r + dy - 1;
            unsigned long long m = 0ULL;
            uint32_t lbit = 0, rbit = 0;
            if (y >= 0 && y < H) {            // zero padding for edge rows
                const uint32_t* row = wb + y * WPR;
                m = (unsigned long long)row[w0] |
                    ((unsigned long long)row[w0 + 1] << 32);
                if (w0 > 0)        lbit = row[w0 - 1] >> 31;   // pixel x0-1
                if (w0 + 2 < WPR)  rbit = row[w0 + 2] & 1u;    // pixel x0+64
            }
            // Shift-safe neighbor extraction (shift counts always <= 63):
            unsigned long long mL = (m << 1) | (unsigned long long)lbit; // bit i = pixel x0+i-1
            unsigned long long mR = (m >> 1) | ((unsigned long long)rbit << 63); // bit i = pixel x0+i+1
            uint32_t b0 = (uint32_t)(mL >> lane) & 1u;  // (y, x-1) -> kx=0
            uint32_t b1 = (uint32_t)(m  >> lane) & 1u;  // (y, x  ) -> kx=1
            uint32_t b2 = (uint32_t)(mR >> lane) & 1u;  // (y, x+1) -> kx=2
            pat |= (b0 | (b1 << 1) | (b2 << 2)) << (3 * dy); // bit k = 3*ky+kx
        }
        atomicAdd(&lh[pat], 1u);
    }
    __syncthreads();

    // Phase 2: lane = channel; waves split the 512 patterns.
    float wk[9];
    #pragma unroll
    for (int k = 0; k < 9; ++k) wk[k] = conv_w[lane * 9 + k];
    float inv   = rsqrtf(bn_v[lane] + 1e-5f);
    float scale = bn_g[lane] * inv;
    float shift = (conv_b[lane] - bn_m[lane]) * scale + bn_b[lane];
    float acc = 0.0f;
    for (int pat = wave; pat < NPAT; pat += 4) {
        uint32_t cnt = lh[pat];               // wave-uniform
        if (cnt) {
            float s = 0.0f;
            #pragma unroll
            for (int k = 0; k < 9; ++k) s += ((pat >> k) & 1u) ? wk[k] : 0.0f;
            float f = fmaxf(fmaf(s, scale, shift), 0.0f);
            acc += (float)cnt * f;
        }
    }
    facc[wave][lane] = acc;
    __syncthreads();
    if (wave == 0) {
        float tot = (facc[0][lane] + facc[1][lane]) + (facc[2][lane] + facc[3][lane]);
        atomicAdd(&out[img * (DIM + 1) + lane], tot * (1.0f / (float)(H * W)));
    }

    // Marker: first 32 bits of image 0, packed MSB-first per byte, vs 'AI24'.
    if (blk == 0 && tid == 0) {
        uint32_t wrd = words[0];
        const int M[4] = {65, 73, 50, 52};
        int ok = 1;
        #pragma unroll
        for (int j = 0; j < 4; ++j) {
            int byte = 0;
            #pragma unroll
            for (int k = 0; k < 8; ++k)
                byte |= (int)((wrd >> (8 * j + k)) & 1u) << (7 - k);
            ok &= (byte == M[j]);
        }
        out[img * (DIM + 1) + DIM] = ok ? 1.0f : 0.0f;
    }
}

extern "C" void kernel_launch(void* const* d_in, const int* in_sizes, int n_in,
                              void* d_out, int out_size, void* d_ws, size_t ws_size,
                              hipStream_t stream) {
    const float* alpha  = (const float*)d_in[0];
    const float* conv_w = (const float*)d_in[1];
    const float* conv_b = (const float*)d_in[2];
    const float* bn_g   = (const float*)d_in[3];
    const float* bn_b   = (const float*)d_in[4];
    const float* bn_m   = (const float*)d_in[5];
    const float* bn_v   = (const float*)d_in[6];
    float* out = (float*)d_out;
    uint32_t* words = (uint32_t*)d_ws;        // 32*384*12*4 = 589,824 B of scratch

    pack_bits_kernel<<<NPIX / 256, 256, 0, stream>>>(alpha, words, out);
    hist_feat_kernel<<<BATCH * BPI, 256, 0, stream>>>(
        words, conv_w, conv_b, bn_g, bn_b, bn_m, bn_v, out);
}

// Round 2
// 89.661 us; speedup vs baseline: 1.6514x; 1.6514x over previous
//
#include <hip/hip_runtime.h>
#include <stdint.h>

#define BATCH 32
#define H 384
#define W 384
#define DIM 64
#define SEGS 6            // 64-pixel segments per row
#define NPAT 512
#define BPI 16            // blocks per image
#define R (H / BPI)       // 24 rows per block
#define BS 512            // threads per block (8 waves)
#define WAVES (BS / 64)

// One fused kernel: pack bits (ballot) -> LDS masks -> 512-bin pattern
// histogram -> Gray-code channel contraction -> global float atomics.
__global__ __launch_bounds__(BS) void fused_alpha_kernel(
    const float* __restrict__ alpha,
    const float* __restrict__ conv_w, const float* __restrict__ conv_b,
    const float* __restrict__ bn_g, const float* __restrict__ bn_b,
    const float* __restrict__ bn_m, const float* __restrict__ bn_v,
    float* __restrict__ out)
{
    __shared__ unsigned long long lmask[R + 2][SEGS];  // rows r0-1 .. r0+R
    __shared__ uint32_t hist[NPAT];
    __shared__ float facc[WAVES][DIM];

    const int tid  = threadIdx.x;
    const int wave = tid >> 6;
    const int lane = tid & 63;
    const int img  = blockIdx.x / BPI;
    const int blk  = blockIdx.x % BPI;
    const int r0   = blk * R;

    if (tid < NPAT) hist[tid] = 0;

    const float* aimg = alpha + img * (H * W);

    // ---- Phase A: pack LSBs into 64-bit row masks in LDS ----------------
    // (R+2)*SEGS = 156 wave-tasks, chunked by 4 so 4 loads are in flight.
    // 156 % 4 == 0 and chunks stride 32, so every chunk is full.
    const int total = (R + 2) * SEGS;
    for (int t0 = wave * 4; t0 < total; t0 += WAVES * 4) {
        float av[4];
        int okv[4];
        #pragma unroll
        for (int i = 0; i < 4; ++i) {
            int t = t0 + i;
            int rr = t / SEGS, s = t - rr * SEGS;
            int y = r0 + rr - 1;
            okv[i] = (y >= 0) && (y < H);
            int yc = min(max(y, 0), H - 1);            // clamp, mask later
            av[i] = aimg[yc * W + s * 64 + lane];      // coalesced 256B/wave
        }
        #pragma unroll
        for (int i = 0; i < 4; ++i) {
            int t = t0 + i;
            int rr = t / SEGS, s = t - rr * SEGS;
            int bit = okv[i] ? (((int)(av[i] * 255.0f)) & 1) : 0;
            unsigned long long mask = __ballot(bit);   // bit l = pixel s*64+l
            if (lane == 0) lmask[rr][s] = mask;
        }
    }
    __syncthreads();

    // ---- Marker check (block 0 = image 0, rows 0..) ---------------------
    if (blockIdx.x == 0 && tid < BATCH) {
        uint32_t wrd = (uint32_t)(lmask[1][0] & 0xFFFFFFFFULL); // row 0, px 0..31
        const int M[4] = {65, 73, 50, 52};                      // 'AI24'
        int ok = 1;
        #pragma unroll
        for (int j = 0; j < 4; ++j) {
            int byte = 0;
            #pragma unroll
            for (int k = 0; k < 8; ++k)
                byte |= (int)((wrd >> (8 * j + k)) & 1u) << (7 - k); // MSB-first
            ok &= (byte == M[j]);
        }
        out[tid * (DIM + 1) + DIM] = (float)ok;  // same flag for all 32 images
    }

    // ---- Phase B: 9-bit neighborhood pattern histogram ------------------
    for (int t = wave; t < R * SEGS; t += WAVES) {
        int rr = t / SEGS;            // output row -> mask rows rr..rr+2
        int s  = t - rr * SEGS;
        uint32_t pat = 0;
        #pragma unroll
        for (int dy = 0; dy < 3; ++dy) {
            int mr = rr + dy;
            unsigned long long m = lmask[mr][s];
            uint32_t lbit = (s > 0)        ? (uint32_t)(lmask[mr][s - 1] >> 63) : 0u;
            uint32_t rbit = (s < SEGS - 1) ? (uint32_t)(lmask[mr][s + 1] & 1ULL) : 0u;
            unsigned long long mL = (m << 1) | (unsigned long long)lbit;
            unsigned long long mR = (m >> 1) | ((unsigned long long)rbit << 63);
            uint32_t b0 = (uint32_t)(mL >> lane) & 1u;   // (y, x-1)
            uint32_t b1 = (uint32_t)(m  >> lane) & 1u;   // (y, x  )
            uint32_t b2 = (uint32_t)(mR >> lane) & 1u;   // (y, x+1)
            pat |= (b0 | (b1 << 1) | (b2 << 2)) << (3 * dy);
        }
        atomicAdd(&hist[pat], 1u);
    }
    __syncthreads();

    // ---- Phase C: contraction. lane = channel; BN scale folded into w. --
    float inv   = rsqrtf(bn_v[lane] + 1e-5f);
    float scale = bn_g[lane] * inv;
    float shift = (conv_b[lane] - bn_m[lane]) * scale + bn_b[lane];
    float wks[9];
    #pragma unroll
    for (int k = 0; k < 9; ++k) wks[k] = conv_w[lane * 9 + k] * scale;

    // wave index supplies pattern bits 6..8; Gray-code walk over bits 0..5.
    float sv = shift;
    if (wave & 1) sv += wks[6];
    if (wave & 2) sv += wks[7];
    if (wave & 4) sv += wks[8];
    const int hibase = wave * 64;
    float acc = 0.0f;
    #pragma unroll
    for (int p = 0; p < 64; ++p) {
        if (p) {  // p compile-time: b, g, sign all fold to constants
            const int b = __builtin_ctz(p);
            const uint32_t g = (uint32_t)(p ^ (p >> 1));
            sv += ((g >> b) & 1u) ? wks[b] : -wks[b];
        }
        uint32_t cnt = hist[hibase + (p ^ (p >> 1))];  // uniform -> broadcast
        acc += (float)cnt * fmaxf(sv, 0.0f);
    }
    facc[wave][lane] = acc;
    __syncthreads();
    if (wave == 0) {
        float tot = 0.0f;
        #pragma unroll
        for (int w2 = 0; w2 < WAVES; ++w2) tot += facc[w2][lane];
        atomicAdd(&out[img * (DIM + 1) + lane], tot * (1.0f / (float)(H * W)));
    }
}

extern "C" void kernel_launch(void* const* d_in, const int* in_sizes, int n_in,
                              void* d_out, int out_size, void* d_ws, size_t ws_size,
                              hipStream_t stream) {
    const float* alpha  = (const float*)d_in[0];
    const float* conv_w = (const float*)d_in[1];
    const float* conv_b = (const float*)d_in[2];
    const float* bn_g   = (const float*)d_in[3];
    const float* bn_b   = (const float*)d_in[4];
    const float* bn_m   = (const float*)d_in[5];
    const float* bn_v   = (const float*)d_in[6];
    float* out = (float*)d_out;

    // d_out is poisoned 0xAA before every launch; zero it on-stream
    // (memset node is graph-capturable), then accumulate with atomics.
    hipMemsetAsync(d_out, 0, (size_t)out_size * sizeof(float), stream);
    fused_alpha_kernel<<<BATCH * BPI, BS, 0, stream>>>(
        alpha, conv_w, conv_b, bn_g, bn_b, bn_m, bn_v, out);
}